// Round 6
// baseline (77.114 us; speedup 1.0000x reference)
//
#include <hip/hip_runtime.h>

#define NB 16
#define LD 128
#define OD 512
#define NS 16384
#define NPMAX (NS + NB*128)      // 18432 max padded rows (128-aligned segments)
#define NFB (NPMAX/64)           // 288 fused blocks (64 rows each)

typedef __attribute__((ext_vector_type(8))) short short8;
typedef __attribute__((ext_vector_type(4))) float f32x4;

// ---- ws byte layout ----
#define WS_OFF     128                           // 17 int
#define WS_POFF    256                           // 17 int
#define WS_PERM    1024                          // NS int (64 KiB)
#define WS_W1B     (128*1024)                    // 16*512*128 bf16 = 2 MiB
#define WS_W2B     (WS_W1B + 2*1024*1024)        // 16*512*512 bf16 = 8 MiB

#define GLDS16(g, l) __builtin_amdgcn_global_load_lds( \
    (const __attribute__((address_space(1))) unsigned int*)(g), \
    (__attribute__((address_space(3))) unsigned int*)(l), 16, 0, 0)

static __device__ __forceinline__ unsigned short f2bf(float f) {
  unsigned int u = __float_as_uint(f);
  u += 0x7FFFu + ((u >> 16) & 1u);      // RNE
  return (unsigned short)(u >> 16);
}

// ---- fused: block 0 = counting sort (1024 thr); blocks 1.. = weight conv ----
#define SORT_T 1024
#define SORT_CH (NS / SORT_T)
__global__ __launch_bounds__(SORT_T) void k_convsort(
    const float* __restrict__ W1, const float* __restrict__ W2,
    const int* __restrict__ c,
    unsigned short* __restrict__ W1b, unsigned short* __restrict__ W2b,
    int* __restrict__ off, int* __restrict__ poff, int* __restrict__ perm) {
  __shared__ int cnt[NB * SORT_T];
  __shared__ int totals[NB];
  __shared__ int ebase[NB];

  const int t = threadIdx.x;
  if (blockIdx.x == 0) {
    for (int e = 0; e < NB; ++e) cnt[e * SORT_T + t] = 0;
    __syncthreads();

    int myc[SORT_CH];
    for (int i = 0; i < SORT_CH; ++i) {
      int e = c[t * SORT_CH + i];
      myc[i] = e;
      cnt[e * SORT_T + t]++;
    }
    __syncthreads();

    const int w = t >> 6, l = t & 63;
    {
      int carry = 0;
      for (int chunk = 0; chunk < SORT_T / 64; ++chunk) {
        int idx = chunk * 64 + l;
        int v0 = cnt[w * SORT_T + idx];
        int v = v0;
        for (int d = 1; d < 64; d <<= 1) {
          int n = __shfl_up(v, d);
          if (l >= d) v += n;
        }
        cnt[w * SORT_T + idx] = carry + (v - v0);
        carry += __shfl(v, 63);
      }
      if (l == 0) totals[w] = carry;
    }
    __syncthreads();

    if (t == 0) {
      int o = 0, p = 0;
      for (int e = 0; e < NB; ++e) {
        off[e] = o; poff[e] = p; ebase[e] = o;
        o += totals[e];
        p += ((totals[e] + 127) >> 7) << 7;    // pad segments to 128 rows
      }
      off[NB] = o; poff[NB] = p;
    }
    __syncthreads();

    for (int i = 0; i < SORT_CH; ++i) {
      int e = myc[i];
      int pos = ebase[e] + cnt[e * SORT_T + t]++;
      perm[pos] = t * SORT_CH + i;
    }
  } else {
    const int n1 = NB * OD * LD / 4, n2 = NB * OD * OD / 4;
    for (int i = (blockIdx.x - 1) * SORT_T + t; i < n1 + n2;
         i += (gridDim.x - 1) * SORT_T) {
      float4 v; unsigned short* dst;
      if (i < n1) { v = ((const float4*)W1)[i]; dst = W1b + (size_t)i * 4; }
      else        { v = ((const float4*)W2)[i - n1]; dst = W2b + (size_t)(i - n1) * 4; }
      ushort4 o = make_ushort4(f2bf(v.x), f2bf(v.y), f2bf(v.z), f2bf(v.w));
      *(ushort4*)dst = o;
    }
  }
}

// ---------- fused MLP: out = (relu(lat@W1^T+b1))@W2^T + b2, hid resident in LDS ----------
// 256 threads (4 waves, 2m x 2n), 64-row M-tile, LDS = 64K hid + 16K stage = 80K (2 blk/CU)
__global__ __launch_bounds__(256) void k_fused(
    const float* __restrict__ eps, const float* __restrict__ mu,
    const float* __restrict__ sigma, const float* __restrict__ b1,
    const float* __restrict__ b2,
    const unsigned short* __restrict__ W1b, const unsigned short* __restrict__ W2b,
    const int* __restrict__ off, const int* __restrict__ poff,
    const int* __restrict__ perm, float* __restrict__ out) {
  __shared__ alignas(16) unsigned short hid[64 * 512];   // 64 KiB, XOR-swizzled
  __shared__ alignas(16) unsigned short sb[8192];        // 16 KiB weight staging

  const int L = blockIdx.x;                 // 288 = 8 * 36
  const int mt = (L & 7) * 36 + (L >> 3);   // bijective XCD-chunk swizzle
  const int pr0 = mt * 64;
  if (pr0 >= poff[NB]) return;
  int e = 0;
  while (e < NB - 1 && poff[e + 1] <= pr0) e++;
  const int off_e = off[e];
  const int cnt   = off[e + 1] - off_e;
  const int l0    = pr0 - poff[e];

  const int t = threadIdx.x, w = t >> 6, lane = t & 63;
  const int wm = w >> 1, wn = w & 1;
  const int fr = lane & 15, fg = lane >> 4;
  // staging lane geometry: per call seg=i*4+w covers rows seg*8..+8 (128B each)
  const int slr = lane >> 3;                               // row within seg
  const int sinner = ((lane & 7) * 16) ^ ((slr & 7) << 4); // pre-swizzled src byte

  // ---- build A1 fragments in registers: rows wm*32..+32, K=128 ----
  short8 a1[2][4];
  int orow[2];   // sample index for A rows (also reused pattern for epilogue)
  {
    int lr0 = l0 + wm * 32 + fr;
    orow[0] = (lr0 + 0  < cnt) ? perm[off_e + lr0] : -1;
    orow[1] = (lr0 + 16 < cnt) ? perm[off_e + lr0 + 16] : -1;
  }
#pragma unroll
  for (int q = 0; q < 4; ++q) {
    const int k0 = q * 32 + fg * 8;
    f32x4 s0 = *(const f32x4*)(sigma + e * LD + k0);
    f32x4 s1 = *(const f32x4*)(sigma + e * LD + k0 + 4);
    f32x4 m0 = *(const f32x4*)(mu + e * LD + k0);
    f32x4 m1 = *(const f32x4*)(mu + e * LD + k0 + 4);
#pragma unroll
    for (int m = 0; m < 2; ++m) {
      short8 o = {};
      if (orow[m] >= 0) {
        f32x4 e0 = *(const f32x4*)(eps + (size_t)orow[m] * LD + k0);
        f32x4 e1 = *(const f32x4*)(eps + (size_t)orow[m] * LD + k0 + 4);
        f32x4 v0 = e0 * s0 + m0, v1 = e1 * s1 + m1;
        o[0] = (short)f2bf(v0[0]); o[1] = (short)f2bf(v0[1]);
        o[2] = (short)f2bf(v0[2]); o[3] = (short)f2bf(v0[3]);
        o[4] = (short)f2bf(v1[0]); o[5] = (short)f2bf(v1[1]);
        o[6] = (short)f2bf(v1[2]); o[7] = (short)f2bf(v1[3]);
      }
      a1[m][q] = o;
    }
  }

  // ---- phase 1: hid = relu(lat @ W1^T + b1), 4 nc-chunks of 128 cols ----
#pragma unroll 1
  for (int nc = 0; nc < 4; ++nc) {
    f32x4 acc1[2][4] = {};
#pragma unroll
    for (int kt1 = 0; kt1 < 2; ++kt1) {
      __syncthreads();   // previous sb readers done
#pragma unroll
      for (int i = 0; i < 4; ++i) {
        const int seg = i * 4 + w;
        const int row = seg * 8 + slr;   // 0..127 = W1 out-col within chunk
        GLDS16((const char*)W1b + ((size_t)(e * OD + nc * 128 + row)) * 256
                   + kt1 * 128 + sinner,
               (char*)sb + seg * 1024);
      }
      __syncthreads();   // drains vmcnt(0): staged data visible
#pragma unroll
      for (int ks = 0; ks < 2; ++ks) {
        short8 b[4];
#pragma unroll
        for (int n = 0; n < 4; ++n) {
          const int cl = wn * 64 + n * 16 + fr;
          b[n] = *(const short8*)((const char*)sb + cl * 128 +
                                  (((ks * 32 + fg * 8) * 2) ^ ((cl & 7) << 4)));
        }
#pragma unroll
        for (int m = 0; m < 2; ++m)
#pragma unroll
          for (int n = 0; n < 4; ++n)
            acc1[m][n] = __builtin_amdgcn_mfma_f32_16x16x32_bf16(
                a1[m][kt1 * 2 + ks], b[n], acc1[m][n], 0, 0, 0);
      }
    }
    // epilogue: bias + relu -> swizzled hid
#pragma unroll
    for (int n = 0; n < 4; ++n) {
      const int col = nc * 128 + wn * 64 + n * 16 + fr;
      const float bv = b1[e * OD + col];
#pragma unroll
      for (int m = 0; m < 2; ++m)
#pragma unroll
        for (int j = 0; j < 4; ++j) {
          const int row = wm * 32 + m * 16 + fg * 4 + j;
          const float v = fmaxf(acc1[m][n][j] + bv, 0.f);
          *(unsigned short*)((char*)hid +
              ((row * 1024 + col * 2) ^ ((row & 7) << 4))) = f2bf(v);
        }
    }
  }

  // ---- phase 2: out = hid @ W2^T + b2, scatter rows via perm ----
  int kout[2][4];
#pragma unroll
  for (int m = 0; m < 2; ++m)
#pragma unroll
    for (int j = 0; j < 4; ++j) {
      const int lr = l0 + wm * 32 + m * 16 + fg * 4 + j;
      kout[m][j] = (lr < cnt) ? perm[off_e + lr] : -1;
    }

#pragma unroll 1
  for (int nc2 = 0; nc2 < 4; ++nc2) {
    f32x4 acc2[2][4] = {};
#pragma unroll 1
    for (int kt = 0; kt < 8; ++kt) {
      __syncthreads();   // previous sb readers done (also hid writes on first iter)
#pragma unroll
      for (int i = 0; i < 4; ++i) {
        const int seg = i * 4 + w;
        const int row = seg * 8 + slr;   // 0..127 = W2 out-col within chunk
        GLDS16((const char*)W2b + ((size_t)(e * OD + nc2 * 128 + row)) * 1024
                   + kt * 128 + sinner,
               (char*)sb + seg * 1024);
      }
      // A fragments from resident hid (independent of stage)
      short8 a2[2][2];
#pragma unroll
      for (int m = 0; m < 2; ++m)
#pragma unroll
        for (int ks = 0; ks < 2; ++ks) {
          const int row = wm * 32 + m * 16 + fr;
          const int kcol = kt * 64 + ks * 32 + fg * 8;
          a2[m][ks] = *(const short8*)((const char*)hid +
              ((row * 1024 + kcol * 2) ^ ((row & 7) << 4)));
        }
      __syncthreads();   // staged W2 visible
#pragma unroll
      for (int ks = 0; ks < 2; ++ks) {
        short8 b[4];
#pragma unroll
        for (int n = 0; n < 4; ++n) {
          const int cl = wn * 64 + n * 16 + fr;
          b[n] = *(const short8*)((const char*)sb + cl * 128 +
                                  (((ks * 32 + fg * 8) * 2) ^ ((cl & 7) << 4)));
        }
#pragma unroll
        for (int m = 0; m < 2; ++m)
#pragma unroll
          for (int n = 0; n < 4; ++n)
            acc2[m][n] = __builtin_amdgcn_mfma_f32_16x16x32_bf16(
                a2[m][ks], b[n], acc2[m][n], 0, 0, 0);
      }
    }
    // epilogue: bias + scatter fp32 rows
#pragma unroll
    for (int n = 0; n < 4; ++n) {
      const int col = nc2 * 128 + wn * 64 + n * 16 + fr;
      const float bv = b2[e * OD + col];
#pragma unroll
      for (int m = 0; m < 2; ++m)
#pragma unroll
        for (int j = 0; j < 4; ++j)
          if (kout[m][j] >= 0)
            out[(size_t)kout[m][j] * OD + col] = acc2[m][n][j] + bv;
    }
  }
}

extern "C" void kernel_launch(void* const* d_in, const int* in_sizes, int n_in,
                              void* d_out, int out_size, void* d_ws, size_t ws_size,
                              hipStream_t stream) {
  const float* eps   = (const float*)d_in[1];
  const int*   c     = (const int*)d_in[2];
  const float* mu    = (const float*)d_in[3];
  const float* sigma = (const float*)d_in[4];
  const float* W1    = (const float*)d_in[5];
  const float* b1    = (const float*)d_in[6];
  const float* W2    = (const float*)d_in[7];
  const float* b2    = (const float*)d_in[8];
  float* out = (float*)d_out;
  char*  ws  = (char*)d_ws;

  int* off     = (int*)(ws + WS_OFF);
  int* poff    = (int*)(ws + WS_POFF);
  int* perm    = (int*)(ws + WS_PERM);
  unsigned short* W1b = (unsigned short*)(ws + WS_W1B);
  unsigned short* W2b = (unsigned short*)(ws + WS_W2B);

  k_convsort<<<512, SORT_T, 0, stream>>>(W1, W2, c, W1b, W2b, off, poff, perm);
  k_fused<<<NFB, 256, 0, stream>>>(eps, mu, sigma, b1, b2, W1b, W2b,
                                   off, poff, perm, out);
}